// Round 7
// baseline (243.046 us; speedup 1.0000x reference)
//
#include <hip/hip_runtime.h>
#include <hip/hip_bf16.h>
#include <stdint.h>

// Problem constants (from reference)
#define N_NODES 50000
#define N_EDGES 800000
#define N_ENTS  200000
#define N_RELS  500
#define DIM     128

#define DEGS 32   // deg counter stride (ints): 1 counter per 128B L2 line
#define CAP  64   // slots per node. deg ~ Poisson(16); P(any node > 64) ~ 1e-20.

// invalid-edge record: points at zeroed dummy rows (afull row 50000, rel row 500)
#define ZERO_REC ((int)(50000u | (500u << 16)))

using f32x4  = __attribute__((ext_vector_type(4))) float;
using bf16x8 = __attribute__((ext_vector_type(8))) short;  // 8 bf16 = 4 VGPRs

static __device__ __forceinline__ ushort f_to_bf16(float f) {
    __hip_bfloat16 h = __float2bfloat16(f);
    return *reinterpret_cast<ushort*>(&h);
}
static __device__ __forceinline__ uint pack2(float a, float b) {
    return (uint)f_to_bf16(a) | ((uint)f_to_bf16(b) << 16);
}
static __device__ __forceinline__ float blo(uint u) { return __uint_as_float(u << 16); }
static __device__ __forceinline__ float bhi(uint u) { return __uint_as_float(u & 0xffff0000u); }

// ---------------------------------------------------------------------------
// K_FRONT: four independent jobs in one launch (block ranges):
//   blk [0,3125):    RANK+SLOT pass: r = atomicAdd(&deg[dst*DEGS],1);
//                    srcpk[dst*CAP+r] = (src|etype<<16)
//   blk [3125,6250): gather h = bf16(prev[node_id]) into h-half of afull rows
//                    afull row layout: [ apre (128) | h (128) ] bf16, stride 256
//   blk [6250,6504): weight-prep: B^T bf16 (WfT) + rel bf16
//   blk 6504:        zero the dummy rows (afull row 50000, rel_bf row 500)
__global__ __launch_bounds__(256) void k_front(
        const float* __restrict__ prev, const int* __restrict__ node_id,
        ushort* __restrict__ afull,
        const int* __restrict__ dst, const int* __restrict__ src,
        const int* __restrict__ etype,
        int* __restrict__ deg, uint* __restrict__ srcpk,
        const float* __restrict__ rel, ushort* __restrict__ rel_bf,
        const float* __restrict__ Wn, const float* __restrict__ Wl,
        ushort* __restrict__ WfT) {
    int blk = blockIdx.x;
    if (blk < 3125) {
        int e = blk * 256 + threadIdx.x;
        if (e < N_EDGES) {
            int dn = dst[e];
            uint rec = (uint)src[e] | ((uint)etype[e] << 16);
            int r = atomicAdd(&deg[dn * DEGS], 1);
            if (r < CAP) srcpk[dn * CAP + r] = rec;
        }
    } else if (blk < 6250) {
        int i = (blk - 3125) * 256 + threadIdx.x;   // 800,000 = N_NODES*16 exactly
        int row = i >> 4, c = (i & 15) * 8;
        int nid = node_id[row];
        const float* p = prev + (size_t)nid * DIM + c;
        float4 v0 = *(const float4*)p;
        float4 v1 = *(const float4*)(p + 4);
        uint4 w;
        w.x = pack2(v0.x, v0.y);
        w.y = pack2(v0.z, v0.w);
        w.z = pack2(v1.x, v1.y);
        w.w = pack2(v1.z, v1.w);
        *(uint4*)(afull + (size_t)row * 256 + 128 + c) = w;
    } else if (blk < 6504) {
        int i = (blk - 6250) * 256 + threadIdx.x;
        if (i < 128 * 256) {            // WfT[n][k] = k<128 ? Wn[k][n] : Wl[k-128][n]
            int n = i >> 8, k = i & 255;
            float v = (k < 128) ? Wn[k * 128 + n] : Wl[(k - 128) * 128 + n];
            WfT[i] = f_to_bf16(v);
        } else {
            int j = i - 128 * 256;      // rel fp32 -> bf16, 2 elems/thread
            if (j < N_RELS * 64) {
                float2 v = *(const float2*)(rel + j * 2);
                *(uint*)(rel_bf + j * 2) = pack2(v.x, v.y);
            }
        }
    } else {
        int t = threadIdx.x;            // zero dummy rows (ws is 0xAA-poisoned)
        if (t < 128)       ((uint*)(afull + (size_t)50000 * 256))[t] = 0u;
        else if (t < 192)  ((uint*)(rel_bf + 500 * 128))[t - 128]    = 0u;
    }
}

// ---------------------------------------------------------------------------
// K_AGG: group-per-node. 16 lanes own one node (4 nodes per wave); grid
// 3125*16 = 50000 exactly. Per edge: one dwordx4 h-row + one dwordx4 rel-row
// per 16-lane group. No cross-group reduction epilogue, no dummy padding
// loads (groups exec-mask off independently; __shfl sources stay in-group).
__global__ __launch_bounds__(256) void k_agg(ushort* __restrict__ afull,
                                             const ushort* __restrict__ rel_bf,
                                             const uint* __restrict__ srcpk,
                                             const int* __restrict__ deg) {
    int wave = threadIdx.x >> 6, lane = threadIdx.x & 63;
    int g = lane >> 4, q = lane & 15;            // group, position-in-group
    int n = blockIdx.x * 16 + wave * 4 + g;      // < 50000 always
    int d = deg[n * DEGS];
    int cnt = min(d, CAP);
    const ushort* hb = afull + 128 + q * 8;      // + srow*256
    const ushort* rb = rel_bf + q * 8;           // + t*128
    float acc[8] = {0.f, 0.f, 0.f, 0.f, 0.f, 0.f, 0.f, 0.f};

#define ACC4(hv, rv)                                                  \
    acc[0] += blo(hv.x) + blo(rv.x); acc[1] += bhi(hv.x) + bhi(rv.x); \
    acc[2] += blo(hv.y) + blo(rv.y); acc[3] += bhi(hv.y) + bhi(rv.y); \
    acc[4] += blo(hv.z) + blo(rv.z); acc[5] += bhi(hv.z) + bhi(rv.z); \
    acc[6] += blo(hv.w) + blo(rv.w); acc[7] += bhi(hv.w) + bhi(rv.w);

    for (int b = 0; b < cnt; b += 16) {
        // lane q preloads record b+q of ITS node; odd tail reads ZERO_REC
        int rec = (b + q < cnt) ? (int)srcpk[n * CAP + b + q] : ZERO_REC;
        int jmax = min(16, cnt - b);
        for (int j = 0; j < jmax; j += 2) {      // 2 edges per group per iter
            uint e0 = (uint)__shfl(rec, (g << 4) + j);
            uint e1 = (uint)__shfl(rec, (g << 4) + j + 1);   // ZERO_REC if j+1==jmax
            uint4 h0 = *(const uint4*)(hb + (size_t)(e0 & 0xffffu) * 256);
            uint4 r0 = *(const uint4*)(rb + (e0 >> 16) * 128);
            uint4 h1 = *(const uint4*)(hb + (size_t)(e1 & 0xffffu) * 256);
            uint4 r1 = *(const uint4*)(rb + (e1 >> 16) * 128);
            ACC4(h0, r0);
            ACC4(h1, r1);
        }
    }
#undef ACC4

    float norm = (d > 0) ? 1.0f / (float)d : 0.0f;
    uint4 w;
    w.x = pack2(acc[0] * norm, acc[1] * norm);
    w.y = pack2(acc[2] * norm, acc[3] * norm);
    w.z = pack2(acc[4] * norm, acc[5] * norm);
    w.w = pack2(acc[6] * norm, acc[7] * norm);
    *(uint4*)(afull + (size_t)n * 256 + q * 8) = w;
}

// ---------------------------------------------------------------------------
// K_MM (+fixup blocks): out = relu( [apre|h] @ [Wn;Wl] ), M=50000,N=128,K=256.
// Blocks [0,391): MFMA GEMM; epilogue SKIPS deg==0 rows.
// Blocks [391,587): fixup scan — deg==0 rows get out = relu(h @ We).
// Writers are disjoint -> safe in one launch.
#define LDSK 264   // padded k-stride (elems): 2-way bank aliasing only (free)
__global__ __launch_bounds__(256) void k_mm(const ushort* __restrict__ afull,
                                            const ushort* __restrict__ WfT,
                                            const int* __restrict__ deg,
                                            const float* __restrict__ We,
                                            float* __restrict__ out) {
    if (blockIdx.x >= 391) {                     // ---- fixup range ----
        int n = (blockIdx.x - 391) * 256 + threadIdx.x;
        if (n < N_NODES && deg[n * DEGS] == 0) { // expected ~0 rows
            for (int c = 0; c < 128; c++) {
                float a = 0.f;
                for (int k = 0; k < 128; k++) {
                    float h = blo((uint)afull[(size_t)n * 256 + 128 + k]);
                    a += h * We[k * 128 + c];
                }
                out[(size_t)n * 128 + c] = a > 0.f ? a : 0.f;
            }
        }
        return;
    }

    __shared__ ushort wl[128 * LDSK];   // 67,584 B
    for (int idx = threadIdx.x; idx < 128 * 32; idx += 256) {
        int n = idx >> 5, p = idx & 31;
        uint4 v = *(const uint4*)(WfT + n * 256 + p * 8);
        *(uint4*)(&wl[n * LDSK + p * 8]) = v;
    }
    __syncthreads();

    int wave = threadIdx.x >> 6, lane = threadIdx.x & 63;
    int m = lane & 15, quad = lane >> 4;
    int rowBase = blockIdx.x * 128 + wave * 32;

    f32x4 acc[2][8];
#pragma unroll
    for (int rt = 0; rt < 2; rt++)
#pragma unroll
        for (int ct = 0; ct < 8; ct++) acc[rt][ct] = f32x4{0.f, 0.f, 0.f, 0.f};

    int r0 = rowBase + m;      if (r0 > N_NODES - 1) r0 = N_NODES - 1;  // clamp tail
    int r1 = rowBase + 16 + m; if (r1 > N_NODES - 1) r1 = N_NODES - 1;
    const ushort* pa0 = afull + (size_t)r0 * 256 + quad * 8;
    const ushort* pa1 = afull + (size_t)r1 * 256 + quad * 8;

#pragma unroll
    for (int ks = 0; ks < 8; ks++) {
        bf16x8 a0 = *(const bf16x8*)(pa0 + ks * 32);   // A[m][k]: k = quad*8+j
        bf16x8 a1 = *(const bf16x8*)(pa1 + ks * 32);
#pragma unroll
        for (int ct = 0; ct < 8; ct++) {
            bf16x8 b = *(const bf16x8*)(&wl[(ct * 16 + m) * LDSK + ks * 32 + quad * 8]);
            acc[0][ct] = __builtin_amdgcn_mfma_f32_16x16x32_bf16(a0, b, acc[0][ct], 0, 0, 0);
            acc[1][ct] = __builtin_amdgcn_mfma_f32_16x16x32_bf16(a1, b, acc[1][ct], 0, 0, 0);
        }
    }

    // epilogue: C/D layout col=lane&15, row=(lane>>4)*4+reg
#pragma unroll
    for (int rt = 0; rt < 2; rt++) {
        int rbase = rowBase + rt * 16 + quad * 4;
#pragma unroll
        for (int reg = 0; reg < 4; reg++) {
            int grow = rbase + reg;
            if (grow < N_NODES && deg[grow * DEGS] != 0) {   // deg==0 -> fixup owns
#pragma unroll
                for (int ct = 0; ct < 8; ct++) {
                    float v = acc[rt][ct][reg];
                    out[(size_t)grow * 128 + ct * 16 + m] = v > 0.f ? v : 0.f;
                }
            }
        }
    }
}

// ---------------------------------------------------------------------------
extern "C" void kernel_launch(void* const* d_in, const int* in_sizes, int n_in,
                              void* d_out, int out_size, void* d_ws, size_t ws_size,
                              hipStream_t stream) {
    const float* prev  = (const float*)d_in[0];  // prev_ent_embs   [200000,128] f32
    const float* rel   = (const float*)d_in[1];  // rel_embs        [500,128]    f32
    const float* Wl    = (const float*)d_in[2];  // loop_weight     [128,128]    f32
    const float* We    = (const float*)d_in[3];  // evolve_loop_w   [128,128]    f32
    const float* Wn    = (const float*)d_in[4];  // weight_neighbor [128,128]    f32
    const int* node_id = (const int*)d_in[5];    // [50000]  int32
    const int* src     = (const int*)d_in[6];    // [800000] int32
    const int* dst     = (const int*)d_in[7];    // [800000] int32
    const int* etype   = (const int*)d_in[8];    // [800000] int32
    float* out = (float*)d_out;                  // [50000,128] f32

    // workspace layout (~45 MB; afull/rel_bf each carry a zeroed dummy row)
    char* ws = (char*)d_ws;
    ushort* afull  = (ushort*)(ws);                 // 25,600,512 B  50001 rows
    ushort* WfT    = (ushort*)(ws + 25600512);      //     65,536 B  B^T bf16
    ushort* rel_bf = (ushort*)(ws + 25666048);      //    128,256 B  501 rows
    int* deg       = (int*)(ws + 25794304);         //  6,400,000 B  deg[n*DEGS]
    uint* srcpk    = (uint*)(ws + 32194304);        // 12,800,000 B  slots [n*CAP+r]

    hipMemsetAsync(deg, 0, 6400000, stream);
    k_front <<<6505, 256, 0, stream>>>(prev, node_id, afull, dst, src, etype,
                                       deg, srcpk, rel, rel_bf, Wn, Wl, WfT);
    k_agg   <<<3125, 256, 0, stream>>>(afull, rel_bf, srcpk, deg);
    k_mm    <<<587,  256, 0, stream>>>(afull, WfT, deg, We, out);
}